// Round 6
// baseline (340.554 us; speedup 1.0000x reference)
//
#include <hip/hip_runtime.h>
#include <math.h>

#define BATCH 4
#define NCH 4
#define H 160
#define W 160
#define NPIX (H * W)          // 25600
#define PRE_K 2048
#define TOPK 500
#define PROB_T 0.75f
#define IOU_T 0.5f
#define COV 10.0f
#define CAP 4096              // LDS rank cap (frontal count fallback to global above this)

// ---- workspace layout (bytes) ----
#define SCORE_OFF 0u                 // float [B][NPIX]
#define FS_OFF    409600u            // float [B][NPIX]  frontal scores (raster order)
#define FIDX_OFF  819200u            // int   [B][NPIX]  frontal pixel idx
#define F_OFF     1228800u           // int   [B]
#define CIDX_OFF  1228864u           // int   [B][PRE_K]
#define CSC_OFF   1261632u           // float [B][PRE_K]
#define CBOX_OFF  1294400u           // float [B][PRE_K][4]
#define SUP_OFF   1425472u           // u32   [B][PRE_K][64]  (row-major, coalesced rows)
#define NV_OFF    3523648u           // int   [B]
#define PAR_OFF   3523712u           // float [B][TOPK][5]  (muy,mux,dy,dx,p)
#define FLAG_OFF  3563712u           // u8    [B][PRE_K]  row-has-any-suppression flags

// out layout (floats)
#define OUT_HEAT_OFF 0
#define OUT_MASK_OFF 102400
#define OUT_BOX_OFF  512000
#define OUT_VAL_OFF  520000

typedef unsigned long long u64;
typedef unsigned int u32;

// -------- block exclusive scan over 256 ints (used by finalize phase) --------
__device__ __forceinline__ int block_scan_excl(int v, int tid, int* tmp, int* total) {
    tmp[tid] = v;
    __syncthreads();
    for (int off = 1; off < 256; off <<= 1) {
        int y = (tid >= off) ? tmp[tid - off] : 0;
        __syncthreads();
        tmp[tid] += y;
        __syncthreads();
    }
    int incl = tmp[tid];
    *total = tmp[255];
    __syncthreads();
    return incl - v;
}

// K1: per-pixel softmax-max / score + mask passthrough copy (fused; removes memcpy node)
__global__ void k_score(const float* __restrict__ mask, float* __restrict__ score,
                        float* __restrict__ out_mask) {
    int b = blockIdx.y;
    int pix = blockIdx.x * 256 + threadIdx.x;
    const float* mp = mask + (size_t)b * NCH * NPIX + pix;
    float* op = out_mask + (size_t)b * NCH * NPIX + pix;
    float x0 = mp[0], x1 = mp[NPIX], x2 = mp[2 * NPIX], x3 = mp[3 * NPIX];
    op[0] = x0; op[NPIX] = x1; op[2 * NPIX] = x2; op[3 * NPIX] = x3;
    float m = x0; int c = 0;
    if (x1 > m) { m = x1; c = 1; }
    if (x2 > m) { m = x2; c = 2; }
    if (x3 > m) { m = x3; c = 3; }
    float sum = ((expf(x0 - m) + expf(x1 - m)) + expf(x2 - m)) + expf(x3 - m);
    float prob = 1.0f / sum;
    bool frontal = (c != 0) && (prob > PROB_T);
    score[(size_t)b * NPIX + pix] = frontal ? prob : -1.0f;
}

// K2: fused compact + exact rank + candidate boxes. One 1024-thread block per image.
// Phase 1: ordered compaction of frontal pixels (raster order; wave-shuffle scan),
//          mirrored into LDS (if F<=CAP) and global (always, for fallback).
//          Padding slots F..PRE_K-1 = first non-frontal pixels (stable top_k pad).
// Phase 2: exact JAX top_k rank (desc score, ties -> lower idx) per frontal item;
//          write cand_idx/cand_score/cand_box at rank.
#define PPT (NPIX / 1024)   // 25
__global__ void __launch_bounds__(1024)
k_select(const float* __restrict__ score, const float* __restrict__ bias,
         float* __restrict__ fs, int* __restrict__ fidx, int* __restrict__ Fout,
         int* __restrict__ cand_idx, float* __restrict__ cand_score,
         float* __restrict__ cand_box) {
    int b = blockIdx.x;
    int tid = threadIdx.x;           // 0..1023
    const float* sc = score + (size_t)b * NPIX;
    const float* bb = bias + (size_t)b * 4 * NPIX;
    int p0 = tid * PPT;
    float v[PPT];
    int cnt = 0;
    #pragma unroll
    for (int j = 0; j < PPT; ++j) {
        v[j] = sc[p0 + j];
        cnt += (v[j] > 0.0f) ? 1 : 0;
    }
    int lane = tid & 63, wv = tid >> 6;
    int incl = cnt;
    for (int off = 1; off < 64; off <<= 1) {
        int y = __shfl_up(incl, off);
        if (lane >= off) incl += y;
    }
    __shared__ int wtot[16];
    __shared__ int wpre[17];
    __shared__ float fs_l[CAP];
    __shared__ int fi_l[CAP];
    if (lane == 63) wtot[wv] = incl;
    __syncthreads();
    if (tid == 0) {
        int acc = 0;
        for (int k = 0; k < 16; ++k) { wpre[k] = acc; acc += wtot[k]; }
        wpre[16] = acc;
    }
    __syncthreads();
    int f_excl = wpre[wv] + (incl - cnt);
    int F = wpre[16];
    if (tid == 0) Fout[b] = F;
    int w = f_excl;
    #pragma unroll
    for (int j = 0; j < PPT; ++j) {
        if (v[j] > 0.0f) {
            fs[(size_t)b * NPIX + w] = v[j];
            fidx[(size_t)b * NPIX + w] = p0 + j;
            if (w < CAP) { fs_l[w] = v[j]; fi_l[w] = p0 + j; }
            ++w;
        }
    }
    // padding slots: first (PRE_K - F) non-frontal pixels, score -1, box included
    if (F < PRE_K) {
        int slot = F + (p0 - f_excl);
        #pragma unroll
        for (int j = 0; j < PPT; ++j) {
            if (!(v[j] > 0.0f)) {
                if (slot < PRE_K) {
                    int pix = p0 + j;
                    cand_idx[(size_t)b * PRE_K + slot] = pix;
                    cand_score[(size_t)b * PRE_K + slot] = -1.0f;
                    float y = (float)(pix / W), x = (float)(pix % W);
                    float4 box;
                    box.x = y + bb[0 * NPIX + pix];
                    box.y = x + bb[1 * NPIX + pix];
                    box.z = y + bb[2 * NPIX + pix];
                    box.w = x + bb[3 * NPIX + pix];
                    ((float4*)cand_box)[(size_t)b * PRE_K + slot] = box;
                }
                ++slot;
            }
        }
    }
    __syncthreads();
    // Phase 2: rank
    bool lds = (F <= CAP);
    for (int i = tid; i < F; i += 1024) {
        float si; int xi;
        if (lds) { si = fs_l[i]; xi = fi_l[i]; }
        else     { si = fs[(size_t)b * NPIX + i]; xi = fidx[(size_t)b * NPIX + i]; }
        int rank = 0;
        if (lds) {
            for (int k = 0; k < F; ++k) {
                float sj = fs_l[k]; int xj = fi_l[k];
                rank += (sj > si || (sj == si && xj < xi)) ? 1 : 0;
            }
        } else {
            for (int k = 0; k < F; ++k) {
                float sj = fs[(size_t)b * NPIX + k]; int xj = fidx[(size_t)b * NPIX + k];
                rank += (sj > si || (sj == si && xj < xi)) ? 1 : 0;
            }
        }
        if (rank < PRE_K) {
            cand_idx[(size_t)b * PRE_K + rank] = xi;
            cand_score[(size_t)b * PRE_K + rank] = si;
            float y = (float)(xi / W), x = (float)(xi % W);
            float4 box;
            box.x = y + bb[0 * NPIX + xi];
            box.y = x + bb[1 * NPIX + xi];
            box.z = y + bb[2 * NPIX + xi];
            box.w = x + bb[3 * NPIX + xi];
            ((float4*)cand_box)[(size_t)b * PRE_K + rank] = box;
        }
    }
}

// K3: suppression bitmatrix, u32 granularity, row-contiguous; per-row nonzero flag.
// Blocks whose 8-row strip lies entirely >= V exit early (those rows are never
// consulted by NMS, which filters r < V).
__global__ void __launch_bounds__(512)
k_iou(const float* __restrict__ cand_box, const int* __restrict__ Fout,
      u32* __restrict__ sup, unsigned char* __restrict__ flag) {
    int b = blockIdx.y;
    int F = Fout[b];
    int V = F < PRE_K ? F : PRE_K;
    int r0 = blockIdx.x * 8;
    if (r0 >= V) return;
    __shared__ float ly1[PRE_K], lx1[PRE_K], ly2[PRE_K], lx2[PRE_K], lar[PRE_K];
    for (int k = threadIdx.x; k < PRE_K; k += 512) {
        float4 v = ((const float4*)cand_box)[(size_t)b * PRE_K + k];
        ly1[k] = v.x; lx1[k] = v.y; ly2[k] = v.z; lx2[k] = v.w;
        lar[k] = (v.z - v.x) * (v.w - v.y);
    }
    __syncthreads();
    int lr = threadIdx.x >> 6;      // 0..7 (one wave per row)
    int w = threadIdx.x & 63;       // 0..63 word lane
    int i = r0 + lr;
    float ay1 = ly1[i], ax1 = lx1[i], ay2 = ly2[i], ax2 = lx2[i], aa = lar[i];
    u32 bits = 0;
    int jbase = w * 32;
    #pragma unroll 4
    for (int jj = 0; jj < 32; ++jj) {
        int jo = (jj + w) & 31;             // bank-conflict-free rotation
        int j = jbase + jo;
        if (j > i) {
            float lty = fmaxf(ay1, ly1[j]);
            float ltx = fmaxf(ax1, lx1[j]);
            float rby = fminf(ay2, ly2[j]);
            float rbx = fminf(ax2, lx2[j]);
            float wy = fmaxf(rby - lty, 0.0f);
            float wx = fmaxf(rbx - ltx, 0.0f);
            float inter = wy * wx;
            float iou = inter / ((aa + lar[j]) - inter);
            if (iou > IOU_T) bits |= (1u << jo);
        }
    }
    sup[((size_t)b * PRE_K + i) * 64 + w] = bits;
    bool any = __any(bits != 0u);
    if (w == 0) flag[(size_t)b * PRE_K + i] = any ? 1 : 0;
}

// K4: fused NMS + finalize. 4 blocks x 256. Wave 0: sparse greedy NMS over the
// ordered nonzero-row list (4-chunk x 8-row register ring pipeline, readlane
// keep checks); keep mask handed to the full block via LDS; 256 threads then
// do the top-500 compaction, outputs, and heat params.
__global__ void __launch_bounds__(256)
k_nmsfin(const u32* __restrict__ sup, const unsigned char* __restrict__ flag,
         const int* __restrict__ Fout, const float* __restrict__ cand_score,
         const float* __restrict__ cand_box, float* __restrict__ out_boxes,
         float* __restrict__ out_valid, float* __restrict__ params,
         int* __restrict__ NV) {
    int b = blockIdx.x;
    int tid = threadIdx.x;
    int F = Fout[b];
    int V = F < PRE_K ? F : PRE_K;
    __shared__ int rid_s[PRE_K];
    __shared__ int M_s;
    __shared__ u32 kws[64];
    __shared__ int tmp[256];

    // ---- wave 0: build ordered nonzero-row list ----
    if (tid < 64) {
        int lane = tid;
        const u32* f32 = (const u32*)(flag + (size_t)b * PRE_K);
        u32 fw[8];
        #pragma unroll
        for (int k = 0; k < 8; ++k) fw[k] = f32[lane * 8 + k];
        int r0 = lane * 32;
        int cnt = 0;
        #pragma unroll
        for (int k = 0; k < 8; ++k)
            #pragma unroll
            for (int j = 0; j < 4; ++j) {
                int r = r0 + k * 4 + j;
                if (((fw[k] >> (8 * j)) & 0xFFu) != 0u && r < V) ++cnt;
            }
        int incl = cnt;
        for (int off = 1; off < 64; off <<= 1) {
            int y = __shfl_up(incl, off);
            if (lane >= off) incl += y;
        }
        if (lane == 63) M_s = incl;
        int pos = incl - cnt;
        #pragma unroll
        for (int k = 0; k < 8; ++k)
            #pragma unroll
            for (int j = 0; j < 4; ++j) {
                int r = r0 + k * 4 + j;
                if (((fw[k] >> (8 * j)) & 0xFFu) != 0u && r < V) rid_s[pos++] = r;
            }
    }
    __syncthreads();

    // ---- wave 0: pipelined greedy NMS ----
    if (tid < 64) {
        int lane = tid;
        int M = M_s;
        int rem = V - lane * 32;
        u32 kw = (rem >= 32) ? 0xFFFFFFFFu : (rem <= 0 ? 0u : ((1u << rem) - 1u));
        const u32* supb = sup + (size_t)b * PRE_K * 64 + lane;  // lane = word index
        int C = (M + 7) >> 3;
        int C4 = (C + 3) & ~3;
        int l7 = lane & 7;
        u32 rbuf[4][8];
        int ridv[4];

        #define LOAD_RID(slot, c) ridv[slot] = rid_s[min((c) * 8 + l7, PRE_K - 1)]
        #define ISSUE(slot) do { \
            _Pragma("unroll") \
            for (int k_ = 0; k_ < 8; ++k_) { \
                int i_ = __builtin_amdgcn_readlane(ridv[slot], k_) & (PRE_K - 1); \
                rbuf[slot][k_] = supb[(size_t)i_ * 64]; \
            } \
        } while (0)
        #define PROC(slot, c) do { \
            _Pragma("unroll") \
            for (int k_ = 0; k_ < 8; ++k_) { \
                int m_ = (c) * 8 + k_; \
                if (m_ < M) { \
                    int i_ = __builtin_amdgcn_readlane(ridv[slot], k_) & (PRE_K - 1); \
                    u32 kb_ = (u32)__builtin_amdgcn_readlane((int)kw, i_ >> 5); \
                    if ((kb_ >> (i_ & 31)) & 1u) kw &= ~rbuf[slot][k_]; \
                } \
            } \
        } while (0)

        LOAD_RID(0, 0); LOAD_RID(1, 1); LOAD_RID(2, 2); LOAD_RID(3, 3);
        ISSUE(0); ISSUE(1); ISSUE(2);
        for (int c = 0; c < C4; c += 4) {
            PROC(0, c);     ISSUE(3);            LOAD_RID(0, c + 4);
            PROC(1, c + 1); ISSUE(0);            LOAD_RID(1, c + 5);
            PROC(2, c + 2); ISSUE(1);            LOAD_RID(2, c + 6);
            PROC(3, c + 3); ISSUE(2);            LOAD_RID(3, c + 7);
        }
        #undef LOAD_RID
        #undef ISSUE
        #undef PROC
        kws[lane] = kw;
    }
    __syncthreads();

    // ---- finalize: top-500 (kept in slot order, then non-kept in slot order) ----
    int s0 = tid * 8;
    int bits8 = (int)((kws[s0 >> 5] >> (s0 & 31)) & 0xFFu);
    int cnt = __popc(bits8);
    int tot;
    int kpre = block_scan_excl(cnt, tid, tmp, &tot);
    int NK = tot;
    for (int k = 0; k < 8; ++k) {
        int s = s0 + k;
        int kept = (bits8 >> k) & 1;
        int pos = kept ? kpre : (NK + s - kpre);
        if (pos < TOPK) {
            float4 bx = ((const float4*)cand_box)[(size_t)b * PRE_K + s];
            ((float4*)out_boxes)[(size_t)b * TOPK + pos] = bx;
            out_valid[(size_t)b * TOPK + pos] = kept ? 1.0f : 0.0f;
            if (kept) {
                float scv = cand_score[(size_t)b * PRE_K + s];
                float* pp = params + ((size_t)b * TOPK + pos) * 5;
                pp[0] = (bx.x + bx.z) * 0.5f;   // muy
                pp[1] = (bx.y + bx.w) * 0.5f;   // mux
                pp[2] = (bx.z - bx.x) / COV;    // sigma_y / cov
                pp[3] = (bx.w - bx.y) / COV;    // sigma_x / cov
                pp[4] = scv;                    // prob
            }
        }
        kpre += kept;
    }
    if (tid == 0) NV[b] = NK < TOPK ? NK : TOPK;
}

// K5: tiled heat map with per-tile Gaussian culling.
#define TILE 16
#define TPL (W / TILE)   // 10 tiles per row
__global__ void k_heat(const float* __restrict__ params, const int* __restrict__ NV,
                       float* __restrict__ heat) {
    int b = blockIdx.y;
    int ty0 = (blockIdx.x / TPL) * TILE;
    int tx0 = (blockIdx.x % TPL) * TILE;
    int tid = threadIdx.x;
    int nv = NV[b];
    __shared__ float lp[TOPK * 5];
    __shared__ int cntS;
    if (tid == 0) cntS = 0;
    __syncthreads();
    for (int t = tid; t < nv; t += 256) {
        const float* pp = params + ((size_t)b * TOPK + t) * 5;
        float muy = pp[0], mux = pp[1], dy = pp[2], dx = pp[3], p = pp[4];
        float cy = fmaxf(fmaxf((float)ty0 - muy, muy - (float)(ty0 + TILE - 1)), 0.0f);
        float cx = fmaxf(fmaxf((float)tx0 - mux, mux - (float)(tx0 + TILE - 1)), 0.0f);
        float zy = cy / fabsf(dy);
        float zx = cx / fabsf(dx);
        float z2 = zy * zy + zx * zx;
        if (!(z2 > 40.0f)) {                 // keep NaN cases
            int idx = atomicAdd(&cntS, 1);
            float* q = lp + idx * 5;
            q[0] = muy; q[1] = mux; q[2] = dy; q[3] = dx; q[4] = p;
        }
    }
    __syncthreads();
    int n = cntS;
    float py = (float)(ty0 + (tid >> 4));
    float px = (float)(tx0 + (tid & 15));
    float m = 0.0f;
    for (int t = 0; t < n; ++t) {
        float muy = lp[t * 5 + 0], mux = lp[t * 5 + 1];
        float dy = lp[t * 5 + 2], dx = lp[t * 5 + 3], p = lp[t * 5 + 4];
        float zy = (py - muy) / dy;
        float zx = (px - mux) / dx;
        float g = expf(-0.5f * (zy * zy + zx * zx)) * p;
        m = fmaxf(m, g);
    }
    heat[(size_t)b * NPIX + (ty0 + (tid >> 4)) * W + tx0 + (tid & 15)] = m;
}

extern "C" void kernel_launch(void* const* d_in, const int* in_sizes, int n_in,
                              void* d_out, int out_size, void* d_ws, size_t ws_size,
                              hipStream_t stream) {
    const float* mask = (const float*)d_in[0];
    const float* bias = (const float*)d_in[1];
    float* out = (float*)d_out;
    char* ws = (char*)d_ws;

    float* score      = (float*)(ws + SCORE_OFF);
    float* fs         = (float*)(ws + FS_OFF);
    int*   fidx       = (int*)(ws + FIDX_OFF);
    int*   Fout       = (int*)(ws + F_OFF);
    int*   cand_idx   = (int*)(ws + CIDX_OFF);
    float* cand_score = (float*)(ws + CSC_OFF);
    float* cand_box   = (float*)(ws + CBOX_OFF);
    u32*   sup        = (u32*)(ws + SUP_OFF);
    int*   NV         = (int*)(ws + NV_OFF);
    float* params     = (float*)(ws + PAR_OFF);
    unsigned char* flag = (unsigned char*)(ws + FLAG_OFF);

    dim3 g100(NPIX / 256, BATCH);
    k_score<<<g100, 256, 0, stream>>>(mask, score, out + OUT_MASK_OFF);
    k_select<<<BATCH, 1024, 0, stream>>>(score, bias, fs, fidx, Fout,
                                         cand_idx, cand_score, cand_box);
    k_iou<<<dim3(PRE_K / 8, BATCH), 512, 0, stream>>>(cand_box, Fout, sup, flag);
    k_nmsfin<<<BATCH, 256, 0, stream>>>(sup, flag, Fout, cand_score, cand_box,
                                        out + OUT_BOX_OFF, out + OUT_VAL_OFF, params, NV);
    k_heat<<<dim3(TPL * (H / TILE), BATCH), 256, 0, stream>>>(params, NV, out + OUT_HEAT_OFF);
}

// Round 7
// 152.112 us; speedup vs baseline: 2.2388x; 2.2388x over previous
//
#include <hip/hip_runtime.h>
#include <math.h>

#define BATCH 4
#define NCH 4
#define H 160
#define W 160
#define NPIX (H * W)          // 25600
#define PRE_K 2048
#define TOPK 500
#define PROB_T 0.75f
#define IOU_T 0.5f
#define COV 10.0f

// ---- workspace layout (bytes) ----
#define SCORE_OFF 0u                 // float [B][NPIX]
#define KEY_OFF   409600u            // u64   [B][NPIX]  packed (score,idx) keys, compacted raster order
#define F_OFF     1228800u           // int   [B]
#define CSC_OFF   1261632u           // float [B][PRE_K]
#define CBOX_OFF  1294400u           // float [B][PRE_K][4]
#define SUP_OFF   1425472u           // u32   [B][PRE_K][64]  (row-major, coalesced rows)
#define NV_OFF    3523648u           // int   [B]
#define PAR_OFF   3523712u           // float [B][TOPK][5]  (muy,mux,dy,dx,p)
#define FLAG_OFF  3563712u           // u8    [B][PRE_K]  row-has-any-suppression flags

// out layout (floats)
#define OUT_HEAT_OFF 0
#define OUT_MASK_OFF 102400
#define OUT_BOX_OFF  512000
#define OUT_VAL_OFF  520000

typedef unsigned long long u64;
typedef unsigned int u32;

// -------- block exclusive scan over 256 ints (used by finalize phase) --------
__device__ __forceinline__ int block_scan_excl(int v, int tid, int* tmp, int* total) {
    tmp[tid] = v;
    __syncthreads();
    for (int off = 1; off < 256; off <<= 1) {
        int y = (tid >= off) ? tmp[tid - off] : 0;
        __syncthreads();
        tmp[tid] += y;
        __syncthreads();
    }
    int incl = tmp[tid];
    *total = tmp[255];
    __syncthreads();
    return incl - v;
}

// K1: per-pixel softmax-max / score + mask passthrough copy (fused)
__global__ void k_score(const float* __restrict__ mask, float* __restrict__ score,
                        float* __restrict__ out_mask) {
    int b = blockIdx.y;
    int pix = blockIdx.x * 256 + threadIdx.x;
    const float* mp = mask + (size_t)b * NCH * NPIX + pix;
    float* op = out_mask + (size_t)b * NCH * NPIX + pix;
    float x0 = mp[0], x1 = mp[NPIX], x2 = mp[2 * NPIX], x3 = mp[3 * NPIX];
    op[0] = x0; op[NPIX] = x1; op[2 * NPIX] = x2; op[3 * NPIX] = x3;
    float m = x0; int c = 0;
    if (x1 > m) { m = x1; c = 1; }
    if (x2 > m) { m = x2; c = 2; }
    if (x3 > m) { m = x3; c = 3; }
    float sum = ((expf(x0 - m) + expf(x1 - m)) + expf(x2 - m)) + expf(x3 - m);
    float prob = 1.0f / sum;
    bool frontal = (c != 0) && (prob > PROB_T);
    score[(size_t)b * NPIX + pix] = frontal ? prob : -1.0f;
}

// K2: ordered compaction -> u64 keys (stable raster order) + padding candidates.
// key = (score_bits << 32) | (0x7FFFFFFF - idx): for positive frontal scores,
// key_j > key_i  <=>  s_j > s_i || (s_j == s_i && idx_j < idx_i)  (JAX top_k order).
// Padding slots F..PRE_K-1 get the first non-frontal pixels (score -1, box built here).
#define PPT (NPIX / 1024)   // 25
__global__ void __launch_bounds__(1024)
k_compact(const float* __restrict__ score, const float* __restrict__ bias,
          u64* __restrict__ keys, int* __restrict__ Fout,
          float* __restrict__ cand_score, float* __restrict__ cand_box) {
    int b = blockIdx.x;
    int tid = threadIdx.x;           // 0..1023
    const float* sc = score + (size_t)b * NPIX;
    const float* bb = bias + (size_t)b * 4 * NPIX;
    int p0 = tid * PPT;
    float v[PPT];
    int cnt = 0;
    #pragma unroll
    for (int j = 0; j < PPT; ++j) {
        v[j] = sc[p0 + j];
        cnt += (v[j] > 0.0f) ? 1 : 0;
    }
    int lane = tid & 63, wv = tid >> 6;
    int incl = cnt;
    for (int off = 1; off < 64; off <<= 1) {
        int y = __shfl_up(incl, off);
        if (lane >= off) incl += y;
    }
    __shared__ int wtot[16];
    __shared__ int wpre[17];
    if (lane == 63) wtot[wv] = incl;
    __syncthreads();
    if (tid == 0) {
        int acc = 0;
        for (int k = 0; k < 16; ++k) { wpre[k] = acc; acc += wtot[k]; }
        wpre[16] = acc;
    }
    __syncthreads();
    int f_excl = wpre[wv] + (incl - cnt);
    int F = wpre[16];
    if (tid == 0) Fout[b] = F;
    int w = f_excl;
    #pragma unroll
    for (int j = 0; j < PPT; ++j) {
        if (v[j] > 0.0f) {
            u32 lo = 0x7FFFFFFFu - (u32)(p0 + j);
            keys[(size_t)b * NPIX + w] = ((u64)__float_as_uint(v[j]) << 32) | (u64)lo;
            ++w;
        }
    }
    // padding slots: first (PRE_K - F) non-frontal pixels, score -1, box built here
    if (F < PRE_K) {
        int slot = F + (p0 - f_excl);
        #pragma unroll
        for (int j = 0; j < PPT; ++j) {
            if (!(v[j] > 0.0f)) {
                if (slot < PRE_K) {
                    int pix = p0 + j;
                    cand_score[(size_t)b * PRE_K + slot] = -1.0f;
                    float y = (float)(pix / W), x = (float)(pix % W);
                    float4 box;
                    box.x = y + bb[0 * NPIX + pix];
                    box.y = x + bb[1 * NPIX + pix];
                    box.z = y + bb[2 * NPIX + pix];
                    box.w = x + bb[3 * NPIX + pix];
                    ((float4*)cand_box)[(size_t)b * PRE_K + slot] = box;
                }
                ++slot;
            }
        }
    }
}

// K3: exact rank via u64 key comparisons. Wide grid (one item/thread, 256/block);
// inner loop reads keys[k] at a wave-uniform address (scalar-cache friendly),
// unrolled x8. Writes cand_score and cand_box at the item's rank.
__global__ void k_rank(const u64* __restrict__ keys, const float* __restrict__ bias,
                       const int* __restrict__ Fout, float* __restrict__ cand_score,
                       float* __restrict__ cand_box) {
    int b = blockIdx.y;
    int F = Fout[b];
    if (blockIdx.x * 256 >= F) return;
    int i = blockIdx.x * 256 + threadIdx.x;
    if (i >= F) return;
    const u64* kb = keys + (size_t)b * NPIX;
    u64 ki = kb[i];
    int rank = 0;
    int k = 0;
    for (; k + 8 <= F; k += 8) {
        rank += (kb[k]     > ki) ? 1 : 0;
        rank += (kb[k + 1] > ki) ? 1 : 0;
        rank += (kb[k + 2] > ki) ? 1 : 0;
        rank += (kb[k + 3] > ki) ? 1 : 0;
        rank += (kb[k + 4] > ki) ? 1 : 0;
        rank += (kb[k + 5] > ki) ? 1 : 0;
        rank += (kb[k + 6] > ki) ? 1 : 0;
        rank += (kb[k + 7] > ki) ? 1 : 0;
    }
    for (; k < F; ++k) rank += (kb[k] > ki) ? 1 : 0;
    if (rank < PRE_K) {
        float si = __uint_as_float((u32)(ki >> 32));
        int xi = 0x7FFFFFFF - (int)(u32)(ki & 0xFFFFFFFFu);
        cand_score[(size_t)b * PRE_K + rank] = si;
        const float* bb = bias + (size_t)b * 4 * NPIX;
        float y = (float)(xi / W), x = (float)(xi % W);
        float4 box;
        box.x = y + bb[0 * NPIX + xi];
        box.y = x + bb[1 * NPIX + xi];
        box.z = y + bb[2 * NPIX + xi];
        box.w = x + bb[3 * NPIX + xi];
        ((float4*)cand_box)[(size_t)b * PRE_K + rank] = box;
    }
}

// K4: suppression bitmatrix, u32 granularity, row-contiguous; per-row nonzero flag.
// Strips entirely >= V exit early (NMS only consults rows < V).
__global__ void __launch_bounds__(512)
k_iou(const float* __restrict__ cand_box, const int* __restrict__ Fout,
      u32* __restrict__ sup, unsigned char* __restrict__ flag) {
    int b = blockIdx.y;
    int F = Fout[b];
    int V = F < PRE_K ? F : PRE_K;
    int r0 = blockIdx.x * 8;
    if (r0 >= V) return;
    __shared__ float ly1[PRE_K], lx1[PRE_K], ly2[PRE_K], lx2[PRE_K], lar[PRE_K];
    for (int k = threadIdx.x; k < PRE_K; k += 512) {
        float4 v = ((const float4*)cand_box)[(size_t)b * PRE_K + k];
        ly1[k] = v.x; lx1[k] = v.y; ly2[k] = v.z; lx2[k] = v.w;
        lar[k] = (v.z - v.x) * (v.w - v.y);
    }
    __syncthreads();
    int lr = threadIdx.x >> 6;      // 0..7 (one wave per row)
    int w = threadIdx.x & 63;       // 0..63 word lane
    int i = r0 + lr;
    float ay1 = ly1[i], ax1 = lx1[i], ay2 = ly2[i], ax2 = lx2[i], aa = lar[i];
    u32 bits = 0;
    int jbase = w * 32;
    #pragma unroll 4
    for (int jj = 0; jj < 32; ++jj) {
        int jo = (jj + w) & 31;             // bank-conflict-free rotation
        int j = jbase + jo;
        if (j > i) {
            float lty = fmaxf(ay1, ly1[j]);
            float ltx = fmaxf(ax1, lx1[j]);
            float rby = fminf(ay2, ly2[j]);
            float rbx = fminf(ax2, lx2[j]);
            float wy = fmaxf(rby - lty, 0.0f);
            float wx = fmaxf(rbx - ltx, 0.0f);
            float inter = wy * wx;
            float iou = inter / ((aa + lar[j]) - inter);
            if (iou > IOU_T) bits |= (1u << jo);
        }
    }
    sup[((size_t)b * PRE_K + i) * 64 + w] = bits;
    bool any = __any(bits != 0u);
    if (w == 0) flag[(size_t)b * PRE_K + i] = any ? 1 : 0;
}

// K5: fused NMS + finalize. Wave 0: sparse greedy NMS over ordered nonzero rows
// (4-chunk x 8-row register ring pipeline, readlane keep checks); then all 256
// threads do the top-500 compaction, outputs, and heat params.
__global__ void __launch_bounds__(256)
k_nmsfin(const u32* __restrict__ sup, const unsigned char* __restrict__ flag,
         const int* __restrict__ Fout, const float* __restrict__ cand_score,
         const float* __restrict__ cand_box, float* __restrict__ out_boxes,
         float* __restrict__ out_valid, float* __restrict__ params,
         int* __restrict__ NV) {
    int b = blockIdx.x;
    int tid = threadIdx.x;
    int F = Fout[b];
    int V = F < PRE_K ? F : PRE_K;
    __shared__ int rid_s[PRE_K];
    __shared__ int M_s;
    __shared__ u32 kws[64];
    __shared__ int tmp[256];

    if (tid < 64) {
        int lane = tid;
        const u32* f32 = (const u32*)(flag + (size_t)b * PRE_K);
        u32 fw[8];
        #pragma unroll
        for (int k = 0; k < 8; ++k) fw[k] = f32[lane * 8 + k];
        int r0 = lane * 32;
        int cnt = 0;
        #pragma unroll
        for (int k = 0; k < 8; ++k)
            #pragma unroll
            for (int j = 0; j < 4; ++j) {
                int r = r0 + k * 4 + j;
                if (((fw[k] >> (8 * j)) & 0xFFu) != 0u && r < V) ++cnt;
            }
        int incl = cnt;
        for (int off = 1; off < 64; off <<= 1) {
            int y = __shfl_up(incl, off);
            if (lane >= off) incl += y;
        }
        if (lane == 63) M_s = incl;
        int pos = incl - cnt;
        #pragma unroll
        for (int k = 0; k < 8; ++k)
            #pragma unroll
            for (int j = 0; j < 4; ++j) {
                int r = r0 + k * 4 + j;
                if (((fw[k] >> (8 * j)) & 0xFFu) != 0u && r < V) rid_s[pos++] = r;
            }
    }
    __syncthreads();

    if (tid < 64) {
        int lane = tid;
        int M = M_s;
        int rem = V - lane * 32;
        u32 kw = (rem >= 32) ? 0xFFFFFFFFu : (rem <= 0 ? 0u : ((1u << rem) - 1u));
        const u32* supb = sup + (size_t)b * PRE_K * 64 + lane;  // lane = word index
        int C = (M + 7) >> 3;
        int C4 = (C + 3) & ~3;
        int l7 = lane & 7;
        u32 rbuf[4][8];
        int ridv[4];

        #define LOAD_RID(slot, c) ridv[slot] = rid_s[min((c) * 8 + l7, PRE_K - 1)]
        #define ISSUE(slot) do { \
            _Pragma("unroll") \
            for (int k_ = 0; k_ < 8; ++k_) { \
                int i_ = __builtin_amdgcn_readlane(ridv[slot], k_) & (PRE_K - 1); \
                rbuf[slot][k_] = supb[(size_t)i_ * 64]; \
            } \
        } while (0)
        #define PROC(slot, c) do { \
            _Pragma("unroll") \
            for (int k_ = 0; k_ < 8; ++k_) { \
                int m_ = (c) * 8 + k_; \
                if (m_ < M) { \
                    int i_ = __builtin_amdgcn_readlane(ridv[slot], k_) & (PRE_K - 1); \
                    u32 kb_ = (u32)__builtin_amdgcn_readlane((int)kw, i_ >> 5); \
                    if ((kb_ >> (i_ & 31)) & 1u) kw &= ~rbuf[slot][k_]; \
                } \
            } \
        } while (0)

        LOAD_RID(0, 0); LOAD_RID(1, 1); LOAD_RID(2, 2); LOAD_RID(3, 3);
        ISSUE(0); ISSUE(1); ISSUE(2);
        for (int c = 0; c < C4; c += 4) {
            PROC(0, c);     ISSUE(3);            LOAD_RID(0, c + 4);
            PROC(1, c + 1); ISSUE(0);            LOAD_RID(1, c + 5);
            PROC(2, c + 2); ISSUE(1);            LOAD_RID(2, c + 6);
            PROC(3, c + 3); ISSUE(2);            LOAD_RID(3, c + 7);
        }
        #undef LOAD_RID
        #undef ISSUE
        #undef PROC
        kws[lane] = kw;
    }
    __syncthreads();

    int s0 = tid * 8;
    int bits8 = (int)((kws[s0 >> 5] >> (s0 & 31)) & 0xFFu);
    int cnt = __popc(bits8);
    int tot;
    int kpre = block_scan_excl(cnt, tid, tmp, &tot);
    int NK = tot;
    for (int k = 0; k < 8; ++k) {
        int s = s0 + k;
        int kept = (bits8 >> k) & 1;
        int pos = kept ? kpre : (NK + s - kpre);
        if (pos < TOPK) {
            float4 bx = ((const float4*)cand_box)[(size_t)b * PRE_K + s];
            ((float4*)out_boxes)[(size_t)b * TOPK + pos] = bx;
            out_valid[(size_t)b * TOPK + pos] = kept ? 1.0f : 0.0f;
            if (kept) {
                float scv = cand_score[(size_t)b * PRE_K + s];
                float* pp = params + ((size_t)b * TOPK + pos) * 5;
                pp[0] = (bx.x + bx.z) * 0.5f;   // muy
                pp[1] = (bx.y + bx.w) * 0.5f;   // mux
                pp[2] = (bx.z - bx.x) / COV;    // sigma_y / cov
                pp[3] = (bx.w - bx.y) / COV;    // sigma_x / cov
                pp[4] = scv;                    // prob
            }
        }
        kpre += kept;
    }
    if (tid == 0) NV[b] = NK < TOPK ? NK : TOPK;
}

// K6: tiled heat map with per-tile Gaussian culling.
#define TILE 16
#define TPL (W / TILE)   // 10 tiles per row
__global__ void k_heat(const float* __restrict__ params, const int* __restrict__ NV,
                       float* __restrict__ heat) {
    int b = blockIdx.y;
    int ty0 = (blockIdx.x / TPL) * TILE;
    int tx0 = (blockIdx.x % TPL) * TILE;
    int tid = threadIdx.x;
    int nv = NV[b];
    __shared__ float lp[TOPK * 5];
    __shared__ int cntS;
    if (tid == 0) cntS = 0;
    __syncthreads();
    for (int t = tid; t < nv; t += 256) {
        const float* pp = params + ((size_t)b * TOPK + t) * 5;
        float muy = pp[0], mux = pp[1], dy = pp[2], dx = pp[3], p = pp[4];
        float cy = fmaxf(fmaxf((float)ty0 - muy, muy - (float)(ty0 + TILE - 1)), 0.0f);
        float cx = fmaxf(fmaxf((float)tx0 - mux, mux - (float)(tx0 + TILE - 1)), 0.0f);
        float zy = cy / fabsf(dy);
        float zx = cx / fabsf(dx);
        float z2 = zy * zy + zx * zx;
        if (!(z2 > 40.0f)) {                 // keep NaN cases
            int idx = atomicAdd(&cntS, 1);
            float* q = lp + idx * 5;
            q[0] = muy; q[1] = mux; q[2] = dy; q[3] = dx; q[4] = p;
        }
    }
    __syncthreads();
    int n = cntS;
    float py = (float)(ty0 + (tid >> 4));
    float px = (float)(tx0 + (tid & 15));
    float m = 0.0f;
    for (int t = 0; t < n; ++t) {
        float muy = lp[t * 5 + 0], mux = lp[t * 5 + 1];
        float dy = lp[t * 5 + 2], dx = lp[t * 5 + 3], p = lp[t * 5 + 4];
        float zy = (py - muy) / dy;
        float zx = (px - mux) / dx;
        float g = expf(-0.5f * (zy * zy + zx * zx)) * p;
        m = fmaxf(m, g);
    }
    heat[(size_t)b * NPIX + (ty0 + (tid >> 4)) * W + tx0 + (tid & 15)] = m;
}

extern "C" void kernel_launch(void* const* d_in, const int* in_sizes, int n_in,
                              void* d_out, int out_size, void* d_ws, size_t ws_size,
                              hipStream_t stream) {
    const float* mask = (const float*)d_in[0];
    const float* bias = (const float*)d_in[1];
    float* out = (float*)d_out;
    char* ws = (char*)d_ws;

    float* score      = (float*)(ws + SCORE_OFF);
    u64*   keys       = (u64*)(ws + KEY_OFF);
    int*   Fout       = (int*)(ws + F_OFF);
    float* cand_score = (float*)(ws + CSC_OFF);
    float* cand_box   = (float*)(ws + CBOX_OFF);
    u32*   sup        = (u32*)(ws + SUP_OFF);
    int*   NV         = (int*)(ws + NV_OFF);
    float* params     = (float*)(ws + PAR_OFF);
    unsigned char* flag = (unsigned char*)(ws + FLAG_OFF);

    dim3 g100(NPIX / 256, BATCH);
    k_score<<<g100, 256, 0, stream>>>(mask, score, out + OUT_MASK_OFF);
    k_compact<<<BATCH, 1024, 0, stream>>>(score, bias, keys, Fout, cand_score, cand_box);
    k_rank<<<g100, 256, 0, stream>>>(keys, bias, Fout, cand_score, cand_box);
    k_iou<<<dim3(PRE_K / 8, BATCH), 512, 0, stream>>>(cand_box, Fout, sup, flag);
    k_nmsfin<<<BATCH, 256, 0, stream>>>(sup, flag, Fout, cand_score, cand_box,
                                        out + OUT_BOX_OFF, out + OUT_VAL_OFF, params, NV);
    k_heat<<<dim3(TPL * (H / TILE), BATCH), 256, 0, stream>>>(params, NV, out + OUT_HEAT_OFF);
}

// Round 8
// 118.527 us; speedup vs baseline: 2.8732x; 1.2834x over previous
//
#include <hip/hip_runtime.h>
#include <math.h>

#define BATCH 4
#define NCH 4
#define H 160
#define W 160
#define NPIX (H * W)          // 25600
#define PRE_K 2048
#define TOPK 500
#define PROB_T 0.75f
#define IOU_T 0.5f
#define COV 10.0f

// ---- workspace layout (bytes) ----
#define SCORE_OFF 0u                 // float [B][NPIX]
#define KEY_OFF   409600u            // u64   [B][NPIX]  packed (score,idx) keys, compacted raster order
#define F_OFF     1228800u           // int   [B]
#define CSC_OFF   1261632u           // float [B][PRE_K]
#define CBOX_OFF  1294400u           // float [B][PRE_K][4]
#define SUP_OFF   1425472u           // u32   [B][PRE_K][64]  (row-major, coalesced rows)
#define NV_OFF    3523648u           // int   [B]
#define PAR_OFF   3523712u           // float [B][TOPK][5]  (muy,mux,dy,dx,p)
#define FLAG_OFF  3563712u           // u8    [B][PRE_K]  row-has-any-suppression flags

// out layout (floats)
#define OUT_HEAT_OFF 0
#define OUT_MASK_OFF 102400
#define OUT_BOX_OFF  512000
#define OUT_VAL_OFF  520000

typedef unsigned long long u64;
typedef unsigned int u32;

// -------- block exclusive scan over 256 ints (used by finalize phase) --------
__device__ __forceinline__ int block_scan_excl(int v, int tid, int* tmp, int* total) {
    tmp[tid] = v;
    __syncthreads();
    for (int off = 1; off < 256; off <<= 1) {
        int y = (tid >= off) ? tmp[tid - off] : 0;
        __syncthreads();
        tmp[tid] += y;
        __syncthreads();
    }
    int incl = tmp[tid];
    *total = tmp[255];
    __syncthreads();
    return incl - v;
}

// K1: per-pixel softmax-max / score + mask passthrough copy (fused)
__global__ void k_score(const float* __restrict__ mask, float* __restrict__ score,
                        float* __restrict__ out_mask) {
    int b = blockIdx.y;
    int pix = blockIdx.x * 256 + threadIdx.x;
    const float* mp = mask + (size_t)b * NCH * NPIX + pix;
    float* op = out_mask + (size_t)b * NCH * NPIX + pix;
    float x0 = mp[0], x1 = mp[NPIX], x2 = mp[2 * NPIX], x3 = mp[3 * NPIX];
    op[0] = x0; op[NPIX] = x1; op[2 * NPIX] = x2; op[3 * NPIX] = x3;
    float m = x0; int c = 0;
    if (x1 > m) { m = x1; c = 1; }
    if (x2 > m) { m = x2; c = 2; }
    if (x3 > m) { m = x3; c = 3; }
    float sum = ((expf(x0 - m) + expf(x1 - m)) + expf(x2 - m)) + expf(x3 - m);
    float prob = 1.0f / sum;
    bool frontal = (c != 0) && (prob > PROB_T);
    score[(size_t)b * NPIX + pix] = frontal ? prob : -1.0f;
}

// K2: ordered compaction -> u64 keys (stable raster order) + padding candidates.
// key = (score_bits << 32) | (0x7FFFFFFF - idx): for positive frontal scores,
// key_j > key_i  <=>  s_j > s_i || (s_j == s_i && idx_j < idx_i)  (JAX top_k order).
#define PPT (NPIX / 1024)   // 25
__global__ void __launch_bounds__(1024)
k_compact(const float* __restrict__ score, const float* __restrict__ bias,
          u64* __restrict__ keys, int* __restrict__ Fout,
          float* __restrict__ cand_score, float* __restrict__ cand_box) {
    int b = blockIdx.x;
    int tid = threadIdx.x;           // 0..1023
    const float* sc = score + (size_t)b * NPIX;
    const float* bb = bias + (size_t)b * 4 * NPIX;
    int p0 = tid * PPT;
    float v[PPT];
    int cnt = 0;
    #pragma unroll
    for (int j = 0; j < PPT; ++j) {
        v[j] = sc[p0 + j];
        cnt += (v[j] > 0.0f) ? 1 : 0;
    }
    int lane = tid & 63, wv = tid >> 6;
    int incl = cnt;
    for (int off = 1; off < 64; off <<= 1) {
        int y = __shfl_up(incl, off);
        if (lane >= off) incl += y;
    }
    __shared__ int wtot[16];
    __shared__ int wpre[17];
    if (lane == 63) wtot[wv] = incl;
    __syncthreads();
    if (tid == 0) {
        int acc = 0;
        for (int k = 0; k < 16; ++k) { wpre[k] = acc; acc += wtot[k]; }
        wpre[16] = acc;
    }
    __syncthreads();
    int f_excl = wpre[wv] + (incl - cnt);
    int F = wpre[16];
    if (tid == 0) Fout[b] = F;
    int w = f_excl;
    #pragma unroll
    for (int j = 0; j < PPT; ++j) {
        if (v[j] > 0.0f) {
            u32 lo = 0x7FFFFFFFu - (u32)(p0 + j);
            keys[(size_t)b * NPIX + w] = ((u64)__float_as_uint(v[j]) << 32) | (u64)lo;
            ++w;
        }
    }
    // padding slots: first (PRE_K - F) non-frontal pixels, score -1, box built here
    if (F < PRE_K) {
        int slot = F + (p0 - f_excl);
        #pragma unroll
        for (int j = 0; j < PPT; ++j) {
            if (!(v[j] > 0.0f)) {
                if (slot < PRE_K) {
                    int pix = p0 + j;
                    cand_score[(size_t)b * PRE_K + slot] = -1.0f;
                    float y = (float)(pix / W), x = (float)(pix % W);
                    float4 box;
                    box.x = y + bb[0 * NPIX + pix];
                    box.y = x + bb[1 * NPIX + pix];
                    box.z = y + bb[2 * NPIX + pix];
                    box.w = x + bb[3 * NPIX + pix];
                    ((float4*)cand_box)[(size_t)b * PRE_K + slot] = box;
                }
                ++slot;
            }
        }
    }
}

// K3: exact rank via u64 key comparisons, LDS-staged. Each block bulk-loads the
// key chunk into LDS (coalesced, 2 HBM round-trips) then compares out of LDS
// (uniform-address ds_read broadcasts, ~3-8 cyc each, unrolled x8).
#define RK_CH 4096   // keys per LDS chunk (32 KB)
__global__ void k_rank(const u64* __restrict__ keys, const float* __restrict__ bias,
                       const int* __restrict__ Fout, float* __restrict__ cand_score,
                       float* __restrict__ cand_box) {
    int b = blockIdx.y;
    int F = Fout[b];
    if (blockIdx.x * 256 >= F) return;
    int i = blockIdx.x * 256 + threadIdx.x;
    const u64* kb = keys + (size_t)b * NPIX;
    u64 ki = (i < F) ? kb[i] : 0;
    int rank = 0;
    __shared__ u64 ks[RK_CH];
    for (int base = 0; base < F; base += RK_CH) {
        int lim = min(RK_CH, F - base);
        __syncthreads();
        for (int k = threadIdx.x; k < lim; k += 256) ks[k] = kb[base + k];
        __syncthreads();
        if (i < F) {
            int k = 0;
            for (; k + 8 <= lim; k += 8) {
                rank += (ks[k]     > ki) ? 1 : 0;
                rank += (ks[k + 1] > ki) ? 1 : 0;
                rank += (ks[k + 2] > ki) ? 1 : 0;
                rank += (ks[k + 3] > ki) ? 1 : 0;
                rank += (ks[k + 4] > ki) ? 1 : 0;
                rank += (ks[k + 5] > ki) ? 1 : 0;
                rank += (ks[k + 6] > ki) ? 1 : 0;
                rank += (ks[k + 7] > ki) ? 1 : 0;
            }
            for (; k < lim; ++k) rank += (ks[k] > ki) ? 1 : 0;
        }
    }
    if (i < F && rank < PRE_K) {
        float si = __uint_as_float((u32)(ki >> 32));
        int xi = 0x7FFFFFFF - (int)(u32)(ki & 0xFFFFFFFFu);
        cand_score[(size_t)b * PRE_K + rank] = si;
        const float* bb = bias + (size_t)b * 4 * NPIX;
        float y = (float)(xi / W), x = (float)(xi % W);
        float4 box;
        box.x = y + bb[0 * NPIX + xi];
        box.y = x + bb[1 * NPIX + xi];
        box.z = y + bb[2 * NPIX + xi];
        box.w = x + bb[3 * NPIX + xi];
        ((float4*)cand_box)[(size_t)b * PRE_K + rank] = box;
    }
}

// K4: suppression bitmatrix, u32 granularity, row-contiguous; per-row nonzero flag.
// Strips entirely >= V exit early (NMS only consults rows < V).
__global__ void __launch_bounds__(512)
k_iou(const float* __restrict__ cand_box, const int* __restrict__ Fout,
      u32* __restrict__ sup, unsigned char* __restrict__ flag) {
    int b = blockIdx.y;
    int F = Fout[b];
    int V = F < PRE_K ? F : PRE_K;
    int r0 = blockIdx.x * 8;
    if (r0 >= V) return;
    __shared__ float ly1[PRE_K], lx1[PRE_K], ly2[PRE_K], lx2[PRE_K], lar[PRE_K];
    for (int k = threadIdx.x; k < PRE_K; k += 512) {
        float4 v = ((const float4*)cand_box)[(size_t)b * PRE_K + k];
        ly1[k] = v.x; lx1[k] = v.y; ly2[k] = v.z; lx2[k] = v.w;
        lar[k] = (v.z - v.x) * (v.w - v.y);
    }
    __syncthreads();
    int lr = threadIdx.x >> 6;      // 0..7 (one wave per row)
    int w = threadIdx.x & 63;       // 0..63 word lane
    int i = r0 + lr;
    float ay1 = ly1[i], ax1 = lx1[i], ay2 = ly2[i], ax2 = lx2[i], aa = lar[i];
    u32 bits = 0;
    int jbase = w * 32;
    #pragma unroll 4
    for (int jj = 0; jj < 32; ++jj) {
        int jo = (jj + w) & 31;             // bank-conflict-free rotation
        int j = jbase + jo;
        if (j > i) {
            float lty = fmaxf(ay1, ly1[j]);
            float ltx = fmaxf(ax1, lx1[j]);
            float rby = fminf(ay2, ly2[j]);
            float rbx = fminf(ax2, lx2[j]);
            float wy = fmaxf(rby - lty, 0.0f);
            float wx = fmaxf(rbx - ltx, 0.0f);
            float inter = wy * wx;
            float iou = inter / ((aa + lar[j]) - inter);
            if (iou > IOU_T) bits |= (1u << jo);
        }
    }
    sup[((size_t)b * PRE_K + i) * 64 + w] = bits;
    bool any = __any(bits != 0u);
    if (w == 0) flag[(size_t)b * PRE_K + i] = any ? 1 : 0;
}

// K5: fused NMS + finalize. Wave 0: sparse greedy NMS over ordered nonzero rows
// (4-chunk x 8-row register ring pipeline, readlane keep checks); then all 256
// threads do the top-500 compaction, outputs, and heat params.
__global__ void __launch_bounds__(256)
k_nmsfin(const u32* __restrict__ sup, const unsigned char* __restrict__ flag,
         const int* __restrict__ Fout, const float* __restrict__ cand_score,
         const float* __restrict__ cand_box, float* __restrict__ out_boxes,
         float* __restrict__ out_valid, float* __restrict__ params,
         int* __restrict__ NV) {
    int b = blockIdx.x;
    int tid = threadIdx.x;
    int F = Fout[b];
    int V = F < PRE_K ? F : PRE_K;
    __shared__ int rid_s[PRE_K];
    __shared__ int M_s;
    __shared__ u32 kws[64];
    __shared__ int tmp[256];

    if (tid < 64) {
        int lane = tid;
        const u32* f32 = (const u32*)(flag + (size_t)b * PRE_K);
        u32 fw[8];
        #pragma unroll
        for (int k = 0; k < 8; ++k) fw[k] = f32[lane * 8 + k];
        int r0 = lane * 32;
        int cnt = 0;
        #pragma unroll
        for (int k = 0; k < 8; ++k)
            #pragma unroll
            for (int j = 0; j < 4; ++j) {
                int r = r0 + k * 4 + j;
                if (((fw[k] >> (8 * j)) & 0xFFu) != 0u && r < V) ++cnt;
            }
        int incl = cnt;
        for (int off = 1; off < 64; off <<= 1) {
            int y = __shfl_up(incl, off);
            if (lane >= off) incl += y;
        }
        if (lane == 63) M_s = incl;
        int pos = incl - cnt;
        #pragma unroll
        for (int k = 0; k < 8; ++k)
            #pragma unroll
            for (int j = 0; j < 4; ++j) {
                int r = r0 + k * 4 + j;
                if (((fw[k] >> (8 * j)) & 0xFFu) != 0u && r < V) rid_s[pos++] = r;
            }
    }
    __syncthreads();

    if (tid < 64) {
        int lane = tid;
        int M = M_s;
        int rem = V - lane * 32;
        u32 kw = (rem >= 32) ? 0xFFFFFFFFu : (rem <= 0 ? 0u : ((1u << rem) - 1u));
        const u32* supb = sup + (size_t)b * PRE_K * 64 + lane;  // lane = word index
        int C = (M + 7) >> 3;
        int C4 = (C + 3) & ~3;
        int l7 = lane & 7;
        u32 rbuf[4][8];
        int ridv[4];

        #define LOAD_RID(slot, c) ridv[slot] = rid_s[min((c) * 8 + l7, PRE_K - 1)]
        #define ISSUE(slot) do { \
            _Pragma("unroll") \
            for (int k_ = 0; k_ < 8; ++k_) { \
                int i_ = __builtin_amdgcn_readlane(ridv[slot], k_) & (PRE_K - 1); \
                rbuf[slot][k_] = supb[(size_t)i_ * 64]; \
            } \
        } while (0)
        #define PROC(slot, c) do { \
            _Pragma("unroll") \
            for (int k_ = 0; k_ < 8; ++k_) { \
                int m_ = (c) * 8 + k_; \
                if (m_ < M) { \
                    int i_ = __builtin_amdgcn_readlane(ridv[slot], k_) & (PRE_K - 1); \
                    u32 kb_ = (u32)__builtin_amdgcn_readlane((int)kw, i_ >> 5); \
                    if ((kb_ >> (i_ & 31)) & 1u) kw &= ~rbuf[slot][k_]; \
                } \
            } \
        } while (0)

        LOAD_RID(0, 0); LOAD_RID(1, 1); LOAD_RID(2, 2); LOAD_RID(3, 3);
        ISSUE(0); ISSUE(1); ISSUE(2);
        for (int c = 0; c < C4; c += 4) {
            PROC(0, c);     ISSUE(3);            LOAD_RID(0, c + 4);
            PROC(1, c + 1); ISSUE(0);            LOAD_RID(1, c + 5);
            PROC(2, c + 2); ISSUE(1);            LOAD_RID(2, c + 6);
            PROC(3, c + 3); ISSUE(2);            LOAD_RID(3, c + 7);
        }
        #undef LOAD_RID
        #undef ISSUE
        #undef PROC
        kws[lane] = kw;
    }
    __syncthreads();

    int s0 = tid * 8;
    int bits8 = (int)((kws[s0 >> 5] >> (s0 & 31)) & 0xFFu);
    int cnt = __popc(bits8);
    int tot;
    int kpre = block_scan_excl(cnt, tid, tmp, &tot);
    int NK = tot;
    for (int k = 0; k < 8; ++k) {
        int s = s0 + k;
        int kept = (bits8 >> k) & 1;
        int pos = kept ? kpre : (NK + s - kpre);
        if (pos < TOPK) {
            float4 bx = ((const float4*)cand_box)[(size_t)b * PRE_K + s];
            ((float4*)out_boxes)[(size_t)b * TOPK + pos] = bx;
            out_valid[(size_t)b * TOPK + pos] = kept ? 1.0f : 0.0f;
            if (kept) {
                float scv = cand_score[(size_t)b * PRE_K + s];
                float* pp = params + ((size_t)b * TOPK + pos) * 5;
                pp[0] = (bx.x + bx.z) * 0.5f;   // muy
                pp[1] = (bx.y + bx.w) * 0.5f;   // mux
                pp[2] = (bx.z - bx.x) / COV;    // sigma_y / cov
                pp[3] = (bx.w - bx.y) / COV;    // sigma_x / cov
                pp[4] = scv;                    // prob
            }
        }
        kpre += kept;
    }
    if (tid == 0) NV[b] = NK < TOPK ? NK : TOPK;
}

// K6: tiled heat map with per-tile Gaussian culling.
#define TILE 16
#define TPL (W / TILE)   // 10 tiles per row
__global__ void k_heat(const float* __restrict__ params, const int* __restrict__ NV,
                       float* __restrict__ heat) {
    int b = blockIdx.y;
    int ty0 = (blockIdx.x / TPL) * TILE;
    int tx0 = (blockIdx.x % TPL) * TILE;
    int tid = threadIdx.x;
    int nv = NV[b];
    __shared__ float lp[TOPK * 5];
    __shared__ int cntS;
    if (tid == 0) cntS = 0;
    __syncthreads();
    for (int t = tid; t < nv; t += 256) {
        const float* pp = params + ((size_t)b * TOPK + t) * 5;
        float muy = pp[0], mux = pp[1], dy = pp[2], dx = pp[3], p = pp[4];
        float cy = fmaxf(fmaxf((float)ty0 - muy, muy - (float)(ty0 + TILE - 1)), 0.0f);
        float cx = fmaxf(fmaxf((float)tx0 - mux, mux - (float)(tx0 + TILE - 1)), 0.0f);
        float zy = cy / fabsf(dy);
        float zx = cx / fabsf(dx);
        float z2 = zy * zy + zx * zx;
        if (!(z2 > 40.0f)) {                 // keep NaN cases
            int idx = atomicAdd(&cntS, 1);
            float* q = lp + idx * 5;
            q[0] = muy; q[1] = mux; q[2] = dy; q[3] = dx; q[4] = p;
        }
    }
    __syncthreads();
    int n = cntS;
    float py = (float)(ty0 + (tid >> 4));
    float px = (float)(tx0 + (tid & 15));
    float m = 0.0f;
    for (int t = 0; t < n; ++t) {
        float muy = lp[t * 5 + 0], mux = lp[t * 5 + 1];
        float dy = lp[t * 5 + 2], dx = lp[t * 5 + 3], p = lp[t * 5 + 4];
        float zy = (py - muy) / dy;
        float zx = (px - mux) / dx;
        float g = expf(-0.5f * (zy * zy + zx * zx)) * p;
        m = fmaxf(m, g);
    }
    heat[(size_t)b * NPIX + (ty0 + (tid >> 4)) * W + tx0 + (tid & 15)] = m;
}

extern "C" void kernel_launch(void* const* d_in, const int* in_sizes, int n_in,
                              void* d_out, int out_size, void* d_ws, size_t ws_size,
                              hipStream_t stream) {
    const float* mask = (const float*)d_in[0];
    const float* bias = (const float*)d_in[1];
    float* out = (float*)d_out;
    char* ws = (char*)d_ws;

    float* score      = (float*)(ws + SCORE_OFF);
    u64*   keys       = (u64*)(ws + KEY_OFF);
    int*   Fout       = (int*)(ws + F_OFF);
    float* cand_score = (float*)(ws + CSC_OFF);
    float* cand_box   = (float*)(ws + CBOX_OFF);
    u32*   sup        = (u32*)(ws + SUP_OFF);
    int*   NV         = (int*)(ws + NV_OFF);
    float* params     = (float*)(ws + PAR_OFF);
    unsigned char* flag = (unsigned char*)(ws + FLAG_OFF);

    dim3 g100(NPIX / 256, BATCH);
    k_score<<<g100, 256, 0, stream>>>(mask, score, out + OUT_MASK_OFF);
    k_compact<<<BATCH, 1024, 0, stream>>>(score, bias, keys, Fout, cand_score, cand_box);
    k_rank<<<g100, 256, 0, stream>>>(keys, bias, Fout, cand_score, cand_box);
    k_iou<<<dim3(PRE_K / 8, BATCH), 512, 0, stream>>>(cand_box, Fout, sup, flag);
    k_nmsfin<<<BATCH, 256, 0, stream>>>(sup, flag, Fout, cand_score, cand_box,
                                        out + OUT_BOX_OFF, out + OUT_VAL_OFF, params, NV);
    k_heat<<<dim3(TPL * (H / TILE), BATCH), 256, 0, stream>>>(params, NV, out + OUT_HEAT_OFF);
}

// Round 9
// 115.485 us; speedup vs baseline: 2.9489x; 1.0263x over previous
//
#include <hip/hip_runtime.h>
#include <math.h>

#define BATCH 4
#define NCH 4
#define H 160
#define W 160
#define NPIX (H * W)          // 25600
#define NTILE (NPIX / 256)    // 100 tiles of 256 pixels
#define PRE_K 2048
#define TOPK 500
#define PROB_T 0.75f
#define IOU_T 0.5f
#define COV 10.0f

// ---- workspace layout (bytes) ----
#define SCORE_OFF 0u                 // float [B][NPIX]
#define KEY_OFF   409600u            // u64   [B][NPIX]  packed (score,idx) keys, compacted raster order
#define F_OFF     1228800u           // int   [B]
#define CSC_OFF   1261632u           // float [B][PRE_K]
#define CBOX_OFF  1294400u           // float [B][PRE_K][4]
#define SUP_OFF   1425472u           // u32   [B][PRE_K][64]  (row-major, coalesced rows)
#define NV_OFF    3523648u           // int   [B]
#define PAR_OFF   3523712u           // float [B][TOPK][5]  (muy,mux,dy,dx,p)
#define FLAG_OFF  3563712u           // u8    [B][PRE_K]  row-has-any-suppression flags
#define BCNT_OFF  3571904u           // int   [B][NTILE] per-tile frontal counts

// out layout (floats)
#define OUT_HEAT_OFF 0
#define OUT_MASK_OFF 102400
#define OUT_BOX_OFF  512000
#define OUT_VAL_OFF  520000

typedef unsigned long long u64;
typedef unsigned int u32;

// -------- block exclusive scan over 256 ints (used by finalize phase) --------
__device__ __forceinline__ int block_scan_excl(int v, int tid, int* tmp, int* total) {
    tmp[tid] = v;
    __syncthreads();
    for (int off = 1; off < 256; off <<= 1) {
        int y = (tid >= off) ? tmp[tid - off] : 0;
        __syncthreads();
        tmp[tid] += y;
        __syncthreads();
    }
    int incl = tmp[tid];
    *total = tmp[255];
    __syncthreads();
    return incl - v;
}

// K1: per-pixel softmax-max / score + mask passthrough copy + per-tile frontal count
__global__ void k_score(const float* __restrict__ mask, float* __restrict__ score,
                        float* __restrict__ out_mask, int* __restrict__ blkcnt) {
    int b = blockIdx.y;
    int pix = blockIdx.x * 256 + threadIdx.x;
    const float* mp = mask + (size_t)b * NCH * NPIX + pix;
    float* op = out_mask + (size_t)b * NCH * NPIX + pix;
    float x0 = mp[0], x1 = mp[NPIX], x2 = mp[2 * NPIX], x3 = mp[3 * NPIX];
    op[0] = x0; op[NPIX] = x1; op[2 * NPIX] = x2; op[3 * NPIX] = x3;
    float m = x0; int c = 0;
    if (x1 > m) { m = x1; c = 1; }
    if (x2 > m) { m = x2; c = 2; }
    if (x3 > m) { m = x3; c = 3; }
    float sum = ((expf(x0 - m) + expf(x1 - m)) + expf(x2 - m)) + expf(x3 - m);
    float prob = 1.0f / sum;
    bool frontal = (c != 0) && (prob > PROB_T);
    score[(size_t)b * NPIX + pix] = frontal ? prob : -1.0f;
    // per-tile frontal count (wave ballot + 4-wave combine)
    __shared__ int wcnt[4];
    u64 bm = __ballot(frontal);
    if ((threadIdx.x & 63) == 0) wcnt[threadIdx.x >> 6] = __popcll(bm);
    __syncthreads();
    if (threadIdx.x == 0)
        blkcnt[b * NTILE + blockIdx.x] = wcnt[0] + wcnt[1] + wcnt[2] + wcnt[3];
}

// K2: WIDE ordered compaction -> u64 keys + padding candidates. 100 blocks/image,
// 1 pixel/thread (fully coalesced). Global base offsets derived from per-tile
// counts; block-local ordered scan completes the exact raster-stable order.
// key = (score_bits << 32) | (0x7FFFFFFF - idx): for positive frontal scores,
// key_j > key_i  <=>  s_j > s_i || (s_j == s_i && idx_j < idx_i)  (JAX top_k order).
__global__ void __launch_bounds__(256)
k_compact(const float* __restrict__ score, const float* __restrict__ bias,
          const int* __restrict__ blkcnt, u64* __restrict__ keys,
          int* __restrict__ Fout, float* __restrict__ cand_score,
          float* __restrict__ cand_box) {
    int b = blockIdx.y;
    int bx = blockIdx.x;
    int tid = threadIdx.x;
    const int* bc = blkcnt + b * NTILE;
    int f_base = 0, F = 0;
    #pragma unroll 4
    for (int k = 0; k < NTILE; ++k) {
        int c = bc[k];
        F += c;
        if (k < bx) f_base += c;
    }
    int pix = bx * 256 + tid;
    float s = score[(size_t)b * NPIX + pix];
    bool fr = (s > 0.0f);
    // block-local ordered scan of fr
    int lane = tid & 63, wv = tid >> 6;
    int v = fr ? 1 : 0;
    int incl = v;
    for (int off = 1; off < 64; off <<= 1) {
        int y = __shfl_up(incl, off);
        if (lane >= off) incl += y;
    }
    __shared__ int wtot[4];
    __shared__ int wpre[4];
    if (lane == 63) wtot[wv] = incl;
    __syncthreads();
    if (tid == 0) {
        int acc = 0;
        for (int k = 0; k < 4; ++k) { wpre[k] = acc; acc += wtot[k]; }
    }
    __syncthreads();
    int f_local = wpre[wv] + (incl - v);   // exclusive frontal prefix within block
    if (fr) {
        u32 lo = 0x7FFFFFFFu - (u32)pix;
        keys[(size_t)b * NPIX + f_base + f_local] =
            ((u64)__float_as_uint(s) << 32) | (u64)lo;
    }
    if (bx == 0 && tid == 0) Fout[b] = F;
    // padding: first (PRE_K - F) non-frontal pixels in raster order
    if (!fr) {
        int nf_base = bx * 256 - f_base;     // non-frontal pixels before this block
        int nf_local = tid - f_local;        // non-frontal before me within block
        int slot = F + nf_base + nf_local;
        if (slot < PRE_K) {
            const float* bb = bias + (size_t)b * 4 * NPIX;
            cand_score[(size_t)b * PRE_K + slot] = -1.0f;
            float y = (float)(pix / W), x = (float)(pix % W);
            float4 box;
            box.x = y + bb[0 * NPIX + pix];
            box.y = x + bb[1 * NPIX + pix];
            box.z = y + bb[2 * NPIX + pix];
            box.w = x + bb[3 * NPIX + pix];
            ((float4*)cand_box)[(size_t)b * PRE_K + slot] = box;
        }
    }
}

// K3: exact rank via u64 key comparisons, LDS-staged.
#define RK_CH 4096   // keys per LDS chunk (32 KB)
__global__ void k_rank(const u64* __restrict__ keys, const float* __restrict__ bias,
                       const int* __restrict__ Fout, float* __restrict__ cand_score,
                       float* __restrict__ cand_box) {
    int b = blockIdx.y;
    int F = Fout[b];
    if (blockIdx.x * 256 >= F) return;
    int i = blockIdx.x * 256 + threadIdx.x;
    const u64* kb = keys + (size_t)b * NPIX;
    u64 ki = (i < F) ? kb[i] : 0;
    int rank = 0;
    __shared__ u64 ks[RK_CH];
    for (int base = 0; base < F; base += RK_CH) {
        int lim = min(RK_CH, F - base);
        __syncthreads();
        for (int k = threadIdx.x; k < lim; k += 256) ks[k] = kb[base + k];
        __syncthreads();
        if (i < F) {
            int k = 0;
            for (; k + 8 <= lim; k += 8) {
                rank += (ks[k]     > ki) ? 1 : 0;
                rank += (ks[k + 1] > ki) ? 1 : 0;
                rank += (ks[k + 2] > ki) ? 1 : 0;
                rank += (ks[k + 3] > ki) ? 1 : 0;
                rank += (ks[k + 4] > ki) ? 1 : 0;
                rank += (ks[k + 5] > ki) ? 1 : 0;
                rank += (ks[k + 6] > ki) ? 1 : 0;
                rank += (ks[k + 7] > ki) ? 1 : 0;
            }
            for (; k < lim; ++k) rank += (ks[k] > ki) ? 1 : 0;
        }
    }
    if (i < F && rank < PRE_K) {
        float si = __uint_as_float((u32)(ki >> 32));
        int xi = 0x7FFFFFFF - (int)(u32)(ki & 0xFFFFFFFFu);
        cand_score[(size_t)b * PRE_K + rank] = si;
        const float* bb = bias + (size_t)b * 4 * NPIX;
        float y = (float)(xi / W), x = (float)(xi % W);
        float4 box;
        box.x = y + bb[0 * NPIX + xi];
        box.y = x + bb[1 * NPIX + xi];
        box.z = y + bb[2 * NPIX + xi];
        box.w = x + bb[3 * NPIX + xi];
        ((float4*)cand_box)[(size_t)b * PRE_K + rank] = box;
    }
}

// K4: suppression bitmatrix, u32 granularity, row-contiguous; per-row nonzero flag.
__global__ void __launch_bounds__(512)
k_iou(const float* __restrict__ cand_box, const int* __restrict__ Fout,
      u32* __restrict__ sup, unsigned char* __restrict__ flag) {
    int b = blockIdx.y;
    int F = Fout[b];
    int V = F < PRE_K ? F : PRE_K;
    int r0 = blockIdx.x * 8;
    if (r0 >= V) return;
    __shared__ float ly1[PRE_K], lx1[PRE_K], ly2[PRE_K], lx2[PRE_K], lar[PRE_K];
    for (int k = threadIdx.x; k < PRE_K; k += 512) {
        float4 v = ((const float4*)cand_box)[(size_t)b * PRE_K + k];
        ly1[k] = v.x; lx1[k] = v.y; ly2[k] = v.z; lx2[k] = v.w;
        lar[k] = (v.z - v.x) * (v.w - v.y);
    }
    __syncthreads();
    int lr = threadIdx.x >> 6;      // 0..7 (one wave per row)
    int w = threadIdx.x & 63;       // 0..63 word lane
    int i = r0 + lr;
    float ay1 = ly1[i], ax1 = lx1[i], ay2 = ly2[i], ax2 = lx2[i], aa = lar[i];
    u32 bits = 0;
    int jbase = w * 32;
    #pragma unroll 4
    for (int jj = 0; jj < 32; ++jj) {
        int jo = (jj + w) & 31;             // bank-conflict-free rotation
        int j = jbase + jo;
        if (j > i) {
            float lty = fmaxf(ay1, ly1[j]);
            float ltx = fmaxf(ax1, lx1[j]);
            float rby = fminf(ay2, ly2[j]);
            float rbx = fminf(ax2, lx2[j]);
            float wy = fmaxf(rby - lty, 0.0f);
            float wx = fmaxf(rbx - ltx, 0.0f);
            float inter = wy * wx;
            float iou = inter / ((aa + lar[j]) - inter);
            if (iou > IOU_T) bits |= (1u << jo);
        }
    }
    sup[((size_t)b * PRE_K + i) * 64 + w] = bits;
    bool any = __any(bits != 0u);
    if (w == 0) flag[(size_t)b * PRE_K + i] = any ? 1 : 0;
}

// K5: fused NMS + finalize.
__global__ void __launch_bounds__(256)
k_nmsfin(const u32* __restrict__ sup, const unsigned char* __restrict__ flag,
         const int* __restrict__ Fout, const float* __restrict__ cand_score,
         const float* __restrict__ cand_box, float* __restrict__ out_boxes,
         float* __restrict__ out_valid, float* __restrict__ params,
         int* __restrict__ NV) {
    int b = blockIdx.x;
    int tid = threadIdx.x;
    int F = Fout[b];
    int V = F < PRE_K ? F : PRE_K;
    __shared__ int rid_s[PRE_K];
    __shared__ int M_s;
    __shared__ u32 kws[64];
    __shared__ int tmp[256];

    if (tid < 64) {
        int lane = tid;
        const u32* f32 = (const u32*)(flag + (size_t)b * PRE_K);
        u32 fw[8];
        #pragma unroll
        for (int k = 0; k < 8; ++k) fw[k] = f32[lane * 8 + k];
        int r0 = lane * 32;
        int cnt = 0;
        #pragma unroll
        for (int k = 0; k < 8; ++k)
            #pragma unroll
            for (int j = 0; j < 4; ++j) {
                int r = r0 + k * 4 + j;
                if (((fw[k] >> (8 * j)) & 0xFFu) != 0u && r < V) ++cnt;
            }
        int incl = cnt;
        for (int off = 1; off < 64; off <<= 1) {
            int y = __shfl_up(incl, off);
            if (lane >= off) incl += y;
        }
        if (lane == 63) M_s = incl;
        int pos = incl - cnt;
        #pragma unroll
        for (int k = 0; k < 8; ++k)
            #pragma unroll
            for (int j = 0; j < 4; ++j) {
                int r = r0 + k * 4 + j;
                if (((fw[k] >> (8 * j)) & 0xFFu) != 0u && r < V) rid_s[pos++] = r;
            }
    }
    __syncthreads();

    if (tid < 64) {
        int lane = tid;
        int M = M_s;
        int rem = V - lane * 32;
        u32 kw = (rem >= 32) ? 0xFFFFFFFFu : (rem <= 0 ? 0u : ((1u << rem) - 1u));
        const u32* supb = sup + (size_t)b * PRE_K * 64 + lane;  // lane = word index
        int C = (M + 7) >> 3;
        int C4 = (C + 3) & ~3;
        int l7 = lane & 7;
        u32 rbuf[4][8];
        int ridv[4];

        #define LOAD_RID(slot, c) ridv[slot] = rid_s[min((c) * 8 + l7, PRE_K - 1)]
        #define ISSUE(slot) do { \
            _Pragma("unroll") \
            for (int k_ = 0; k_ < 8; ++k_) { \
                int i_ = __builtin_amdgcn_readlane(ridv[slot], k_) & (PRE_K - 1); \
                rbuf[slot][k_] = supb[(size_t)i_ * 64]; \
            } \
        } while (0)
        #define PROC(slot, c) do { \
            _Pragma("unroll") \
            for (int k_ = 0; k_ < 8; ++k_) { \
                int m_ = (c) * 8 + k_; \
                if (m_ < M) { \
                    int i_ = __builtin_amdgcn_readlane(ridv[slot], k_) & (PRE_K - 1); \
                    u32 kb_ = (u32)__builtin_amdgcn_readlane((int)kw, i_ >> 5); \
                    if ((kb_ >> (i_ & 31)) & 1u) kw &= ~rbuf[slot][k_]; \
                } \
            } \
        } while (0)

        LOAD_RID(0, 0); LOAD_RID(1, 1); LOAD_RID(2, 2); LOAD_RID(3, 3);
        ISSUE(0); ISSUE(1); ISSUE(2);
        for (int c = 0; c < C4; c += 4) {
            PROC(0, c);     ISSUE(3);            LOAD_RID(0, c + 4);
            PROC(1, c + 1); ISSUE(0);            LOAD_RID(1, c + 5);
            PROC(2, c + 2); ISSUE(1);            LOAD_RID(2, c + 6);
            PROC(3, c + 3); ISSUE(2);            LOAD_RID(3, c + 7);
        }
        #undef LOAD_RID
        #undef ISSUE
        #undef PROC
        kws[lane] = kw;
    }
    __syncthreads();

    int s0 = tid * 8;
    int bits8 = (int)((kws[s0 >> 5] >> (s0 & 31)) & 0xFFu);
    int cnt = __popc(bits8);
    int tot;
    int kpre = block_scan_excl(cnt, tid, tmp, &tot);
    int NK = tot;
    for (int k = 0; k < 8; ++k) {
        int s = s0 + k;
        int kept = (bits8 >> k) & 1;
        int pos = kept ? kpre : (NK + s - kpre);
        if (pos < TOPK) {
            float4 bx = ((const float4*)cand_box)[(size_t)b * PRE_K + s];
            ((float4*)out_boxes)[(size_t)b * TOPK + pos] = bx;
            out_valid[(size_t)b * TOPK + pos] = kept ? 1.0f : 0.0f;
            if (kept) {
                float scv = cand_score[(size_t)b * PRE_K + s];
                float* pp = params + ((size_t)b * TOPK + pos) * 5;
                pp[0] = (bx.x + bx.z) * 0.5f;   // muy
                pp[1] = (bx.y + bx.w) * 0.5f;   // mux
                pp[2] = (bx.z - bx.x) / COV;    // sigma_y / cov
                pp[3] = (bx.w - bx.y) / COV;    // sigma_x / cov
                pp[4] = scv;                    // prob
            }
        }
        kpre += kept;
    }
    if (tid == 0) NV[b] = NK < TOPK ? NK : TOPK;
}

// K6: tiled heat map with per-tile Gaussian culling.
#define TILE 16
#define TPL (W / TILE)   // 10 tiles per row
__global__ void k_heat(const float* __restrict__ params, const int* __restrict__ NV,
                       float* __restrict__ heat) {
    int b = blockIdx.y;
    int ty0 = (blockIdx.x / TPL) * TILE;
    int tx0 = (blockIdx.x % TPL) * TILE;
    int tid = threadIdx.x;
    int nv = NV[b];
    __shared__ float lp[TOPK * 5];
    __shared__ int cntS;
    if (tid == 0) cntS = 0;
    __syncthreads();
    for (int t = tid; t < nv; t += 256) {
        const float* pp = params + ((size_t)b * TOPK + t) * 5;
        float muy = pp[0], mux = pp[1], dy = pp[2], dx = pp[3], p = pp[4];
        float cy = fmaxf(fmaxf((float)ty0 - muy, muy - (float)(ty0 + TILE - 1)), 0.0f);
        float cx = fmaxf(fmaxf((float)tx0 - mux, mux - (float)(tx0 + TILE - 1)), 0.0f);
        float zy = cy / fabsf(dy);
        float zx = cx / fabsf(dx);
        float z2 = zy * zy + zx * zx;
        if (!(z2 > 40.0f)) {                 // keep NaN cases
            int idx = atomicAdd(&cntS, 1);
            float* q = lp + idx * 5;
            q[0] = muy; q[1] = mux; q[2] = dy; q[3] = dx; q[4] = p;
        }
    }
    __syncthreads();
    int n = cntS;
    float py = (float)(ty0 + (tid >> 4));
    float px = (float)(tx0 + (tid & 15));
    float m = 0.0f;
    for (int t = 0; t < n; ++t) {
        float muy = lp[t * 5 + 0], mux = lp[t * 5 + 1];
        float dy = lp[t * 5 + 2], dx = lp[t * 5 + 3], p = lp[t * 5 + 4];
        float zy = (py - muy) / dy;
        float zx = (px - mux) / dx;
        float g = expf(-0.5f * (zy * zy + zx * zx)) * p;
        m = fmaxf(m, g);
    }
    heat[(size_t)b * NPIX + (ty0 + (tid >> 4)) * W + tx0 + (tid & 15)] = m;
}

extern "C" void kernel_launch(void* const* d_in, const int* in_sizes, int n_in,
                              void* d_out, int out_size, void* d_ws, size_t ws_size,
                              hipStream_t stream) {
    const float* mask = (const float*)d_in[0];
    const float* bias = (const float*)d_in[1];
    float* out = (float*)d_out;
    char* ws = (char*)d_ws;

    float* score      = (float*)(ws + SCORE_OFF);
    u64*   keys       = (u64*)(ws + KEY_OFF);
    int*   Fout       = (int*)(ws + F_OFF);
    float* cand_score = (float*)(ws + CSC_OFF);
    float* cand_box   = (float*)(ws + CBOX_OFF);
    u32*   sup        = (u32*)(ws + SUP_OFF);
    int*   NV         = (int*)(ws + NV_OFF);
    float* params     = (float*)(ws + PAR_OFF);
    unsigned char* flag = (unsigned char*)(ws + FLAG_OFF);
    int*   blkcnt     = (int*)(ws + BCNT_OFF);

    dim3 g100(NTILE, BATCH);
    k_score<<<g100, 256, 0, stream>>>(mask, score, out + OUT_MASK_OFF, blkcnt);
    k_compact<<<g100, 256, 0, stream>>>(score, bias, blkcnt, keys, Fout,
                                        cand_score, cand_box);
    k_rank<<<g100, 256, 0, stream>>>(keys, bias, Fout, cand_score, cand_box);
    k_iou<<<dim3(PRE_K / 8, BATCH), 512, 0, stream>>>(cand_box, Fout, sup, flag);
    k_nmsfin<<<BATCH, 256, 0, stream>>>(sup, flag, Fout, cand_score, cand_box,
                                        out + OUT_BOX_OFF, out + OUT_VAL_OFF, params, NV);
    k_heat<<<dim3(TPL * (H / TILE), BATCH), 256, 0, stream>>>(params, NV, out + OUT_HEAT_OFF);
}